// Round 1
// baseline (898.074 us; speedup 1.0000x reference)
//
#include <hip/hip_runtime.h>
#include <math.h>

// ---------------------------------------------------------------------------
// S4 convolution:
//   y[b,l,h] = sum_{t<=l} Keff[l-t] * u[b,t,h] + D * u[b,l,h]
//   Keff[j]  = K[2047-j],  K[t] = C * A_bar^t * B_bar
//   A_bar = expm(dt*A)  (HiPPO-LegS A, lower triangular, eig = -(i+1))
//   B_bar = A^-1 (A_bar - I) B
// Kernel 1 (1 block): builds Keff into ws.
// Kernel 2 (1024 blocks): triangular Toeplitz GEMM, fp32, fused D-skip.
// ---------------------------------------------------------------------------

#define SWMASK 28  // swizzle: element (r,c) at r*64 + (c ^ (r & 28))

__device__ __forceinline__ int swz(int r, int c) {
  return (r << 6) + (c ^ (r & SWMASK));
}

// A entry exactly as the reference builds it (float64 math, cast to fp32)
__device__ __forceinline__ float Aval(int i, int j) {
  if (i > j)  return -(float)(sqrt(2.0 * i + 1.0) * sqrt(2.0 * j + 1.0));
  if (i == j) return -(float)(i + 1);
  return 0.0f;
}

// 64x64x64 matmul in swizzled LDS layout. out = L*R (+ cI*I + cX*X if addG).
// 256 threads, 4x4 tile per thread; both operand fragments are b128 reads.
__device__ __forceinline__ void mm64(float* out, const float* L, const float* R,
                                     const float* Xg, float cI, float cX,
                                     int addG, int tid) {
  __syncthreads();
  const int r0 = (tid & 15) << 2;
  const int c0 = (tid >> 4) << 2;
  float acc[4][4];
#pragma unroll
  for (int i = 0; i < 4; ++i)
#pragma unroll
    for (int j = 0; j < 4; ++j) acc[i][j] = 0.f;

#pragma unroll 4
  for (int k4 = 0; k4 < 64; k4 += 4) {
    float4 a[4], b[4];
#pragma unroll
    for (int i = 0; i < 4; ++i)
      a[i] = *(const float4*)&L[((r0 + i) << 6) + (k4 ^ ((r0 + i) & SWMASK))];
#pragma unroll
    for (int d = 0; d < 4; ++d)
      b[d] = *(const float4*)&R[((k4 + d) << 6) + (c0 ^ ((k4 + d) & SWMASK))];
    float bv[4][4];
#pragma unroll
    for (int d = 0; d < 4; ++d) {
      bv[d][0] = b[d].x; bv[d][1] = b[d].y; bv[d][2] = b[d].z; bv[d][3] = b[d].w;
    }
#pragma unroll
    for (int i = 0; i < 4; ++i) {
      float av[4];
      av[0] = a[i].x; av[1] = a[i].y; av[2] = a[i].z; av[3] = a[i].w;
#pragma unroll
      for (int d = 0; d < 4; ++d)
#pragma unroll
        for (int j = 0; j < 4; ++j) acc[i][j] += av[d] * bv[d][j];
    }
  }
  if (addG) {
#pragma unroll
    for (int i = 0; i < 4; ++i)
#pragma unroll
      for (int j = 0; j < 4; ++j) {
        int r = r0 + i, c = c0 + j;
        float g = cX * Xg[swz(r, c)];
        if (r == c) g += cI;
        acc[i][j] += g;
      }
  }
#pragma unroll
  for (int i = 0; i < 4; ++i) {
    float4 v = make_float4(acc[i][0], acc[i][1], acc[i][2], acc[i][3]);
    *(float4*)&out[((r0 + i) << 6) + (c0 ^ ((r0 + i) & SWMASK))] = v;
  }
  __syncthreads();
}

__global__ __launch_bounds__(256) void prep_kernel(
    const float* __restrict__ B_ssm, const float* __restrict__ C_ssm,
    const float* __restrict__ log_dt, float* __restrict__ keff) {
  __shared__ float buf0[4096];  // X, later vT[comp][t]
  __shared__ float buf1[4096];  // X2, later scratch + R ping + wT
  __shared__ float buf2[4096];  // P ping-pong
  __shared__ float buf3[4096];  // P ping-pong
  const int tid = threadIdx.x;

  const float dtf = expf(log_dt[0]);

  // ||A||_1 (max abs column sum) -> scaling exponent s
  float* red = buf1 + 2432;
  if (tid < 64) {
    int j = tid;
    double colsum = (double)(j + 1);
    double pj = sqrt(2.0 * j + 1.0);
    for (int i = j + 1; i < 64; ++i) colsum += pj * sqrt(2.0 * i + 1.0);
    red[j] = (float)colsum;
  }
  __syncthreads();
  float maxc = 0.f;
  for (int j = 0; j < 64; ++j) maxc = fmaxf(maxc, red[j]);
  const float eta = dtf * maxc;
  int sExp;
  { int e; frexpf(eta, &e); sExp = e > 0 ? e : 0; }  // ||dtA/2^s||_1 < 1
  const float scale = ldexpf(dtf, -sExp);

  // X = (dt/2^s) * A (swizzled)
  for (int idx = tid; idx < 4096; idx += 256) {
    int r = idx >> 6, c = idx & 63;
    buf0[swz(r, c)] = scale * Aval(r, c);
  }

  // X2 = X*X   (mm64's leading barrier publishes X; red already consumed)
  mm64(buf1, buf0, buf0, nullptr, 0.f, 0.f, 0, tid);

  // 1/k! on the fly (uniform scalar work)
  auto invfact = [](int k) -> float {
    double f = 1.0;
    for (int q = 2; q <= k; ++q) f *= q;
    return (float)(1.0 / f);
  };

  // Taylor order-15, degree-2 PS Horner: P = G7; P = P*X2 + Gm, m=6..0
  {
    float cI = invfact(14), cX = invfact(15);
    for (int idx = tid; idx < 4096; idx += 256) {
      int r = idx >> 6, c = idx & 63;
      float g = cX * buf0[swz(r, c)];
      if (r == c) g += cI;
      buf2[swz(r, c)] = g;
    }
  }
  float* Pc = buf2;
  float* Pn = buf3;
  for (int m = 6; m >= 0; --m) {
    mm64(Pn, Pc, buf1, buf0, invfact(2 * m), invfact(2 * m + 1), 1, tid);
    float* t = Pc; Pc = Pn; Pn = t;
  }
  // squarings: E <- E*E, s times  -> A_bar
  for (int q = 0; q < sExp; ++q) {
    mm64(Pn, Pc, Pc, nullptr, 0.f, 0.f, 0, tid);
    float* t = Pc; Pc = Pn; Pn = t;
  }
  float* ABAR = Pc;
  float* PB = Pn;

  // preload A_bar rows: thread (i=tid&63, g=tid>>6) holds A_bar[i][16g..16g+15]
  const int li = tid & 63, lg = tid >> 6;
  float areg[16];
#pragma unroll
  for (int q = 0; q < 16; ++q) areg[q] = ABAR[swz(li, lg * 16 + q)];

  // rhs = (A_bar - I) B ; then forward-substitution solve A x = rhs (double)
  float* pbuf = buf1 + 2048;  // X2 dead after PS
  {
    float p = 0.f;
#pragma unroll
    for (int q = 0; q < 16; ++q) p += areg[q] * B_ssm[lg * 16 + q];
    pbuf[lg * 64 + li] = p;
  }
  __syncthreads();
  double* xd = (double*)(buf1 + 2304);
  if (tid < 64) {
    float rhs = pbuf[tid] + pbuf[64 + tid] + pbuf[128 + tid] + pbuf[192 + tid]
                - B_ssm[tid];
    xd[tid] = (double)rhs;
  }
  __syncthreads();
  for (int j = 0; j < 64; ++j) {
    if (tid == j) xd[j] = xd[j] / (double)Aval(j, j);
    __syncthreads();
    if (tid < 64 && tid > j) xd[tid] -= (double)Aval(tid, j) * xd[j];
    __syncthreads();
  }

  // Phase A: vT[i][t] = (A_bar^t B_bar)[i], t=0..63, stored vT[i*64+t] in buf0
  float* vT = buf0;  // X dead
  if (tid < 64) vT[(tid << 6) + 0] = (float)xd[tid];
  __syncthreads();
  for (int t = 1; t < 64; ++t) {
    float p = 0.f;
#pragma unroll
    for (int q = 0; q < 16; ++q)
      p += areg[q] * vT[((lg * 16 + q) << 6) + (t - 1)];
    pbuf[lg * 64 + li] = p;
    __syncthreads();
    if (tid < 64)
      vT[(tid << 6) + t] =
          pbuf[tid] + pbuf[64 + tid] + pbuf[128 + tid] + pbuf[192 + tid];
    __syncthreads();
  }

  // R = A_bar^64 via 6 more squarings, ping-pong buf1 <-> PB (buf0 preserved)
  float* rcur = ABAR;
  for (int q = 0; q < 6; ++q) {
    float* dst = (q & 1) ? PB : buf1;
    mm64(dst, rcur, rcur, nullptr, 0.f, 0.f, 0, tid);
    rcur = dst;
  }
  float* Rm = rcur;  // = PB after 6 steps

  // Phase B: wT[j][t] = (C R^t)[j], t=0..31, stored wT[j*32+t] in buf1[0..2047]
  float* wT = buf1;
  float* pbuf2 = buf1 + 2048;
  if (tid < 64) wT[(tid << 5) + 0] = C_ssm[tid];
  __syncthreads();
  for (int t = 1; t < 32; ++t) {
    float p = 0.f;
#pragma unroll
    for (int q = 0; q < 16; ++q) {
      int k = lg * 16 + q;
      p += wT[(k << 5) + (t - 1)] * Rm[swz(k, li)];
    }
    pbuf2[lg * 64 + li] = p;
    __syncthreads();
    if (tid < 64)
      wT[(tid << 5) + t] =
          pbuf2[tid] + pbuf2[64 + tid] + pbuf2[128 + tid] + pbuf2[192 + tid];
    __syncthreads();
  }

  // Phase C: K[t] = w[t>>6] . v[t&63];  Keff[j] = K[2047-j]
  for (int t = tid; t < 2048; t += 256) {
    int th = t >> 6, tl = t & 63;
    float dot = 0.f;
#pragma unroll 8
    for (int q = 0; q < 64; ++q)
      dot += wT[(q << 5) + th] * vT[(q << 6) + tl];
    keff[2047 - t] = dot;
  }
}

// ---------------------------------------------------------------------------
// Triangular Toeplitz GEMM: per batch b, Y = T * U, T[l][t] = Keff[l-t] (l>=t)
// 128x128 tile, BK=16, 8x8 per thread, k-tiles above diagonal skipped.
// ---------------------------------------------------------------------------
#define BM 128
#define BN 128
#define BKC 16

__global__ __launch_bounds__(256) void conv_kernel(
    const float* __restrict__ u, const float* __restrict__ keff,
    const float* __restrict__ D_skip, float* __restrict__ y) {
  __shared__ float Kl[2048];
  __shared__ float As[BKC][BM];
  __shared__ float Us[BKC][BN];
  const int tid = threadIdx.x;
  const int bid = blockIdx.x;
  const int bn = bid & 3;
  const int bm = 15 - ((bid >> 2) & 15);  // heavy (long-k) blocks first
  const int b = bid >> 6;
  const int l0 = bm * BM;
  const int h0 = bn * BN;

  for (int i = tid; i < 2048; i += 256) Kl[i] = keff[i];

  const int mf = (tid >> 4) << 3;
  const int nf = (tid & 15) << 3;
  float acc[8][8];
#pragma unroll
  for (int i = 0; i < 8; ++i)
#pragma unroll
    for (int j = 0; j < 8; ++j) acc[i][j] = 0.f;

  const int ktiles = 8 * bm + 8;  // tiles with k0 <= l0+127
  for (int kt = 0; kt < ktiles; ++kt) {
    const int k0 = kt * BKC;
    __syncthreads();
    // stage As[kk][m] = Keff[l0+m-k0-kk] (0 if negative)
    {
      int base = tid << 3;
      int kk = base >> 7, m = base & 127;
      int d0 = l0 + m - k0 - kk;
#pragma unroll
      for (int qq = 0; qq < 8; ++qq) {
        int d = d0 + qq;
        As[kk][m + qq] = (d >= 0) ? Kl[d] : 0.f;
      }
    }
    // stage Us[0..15][0..127], fully coalesced float4 loads
    {
      int row = tid >> 5;           // 0..7
      int c4 = (tid & 31) << 2;     // 0..124
      const float* s0 = u + ((b * 2048 + k0 + row) * 512 + h0 + c4);
      const float* s1 = u + ((b * 2048 + k0 + row + 8) * 512 + h0 + c4);
      *(float4*)&Us[row][c4] = *(const float4*)s0;
      *(float4*)&Us[row + 8][c4] = *(const float4*)s1;
    }
    __syncthreads();
#pragma unroll
    for (int kk = 0; kk < BKC; ++kk) {
      float4 a0 = *(const float4*)&As[kk][mf];
      float4 a1 = *(const float4*)&As[kk][mf + 4];
      float4 b0 = *(const float4*)&Us[kk][nf];
      float4 b1 = *(const float4*)&Us[kk][nf + 4];
      float av[8] = {a0.x, a0.y, a0.z, a0.w, a1.x, a1.y, a1.z, a1.w};
      float bv[8] = {b0.x, b0.y, b0.z, b0.w, b1.x, b1.y, b1.z, b1.w};
#pragma unroll
      for (int i = 0; i < 8; ++i)
#pragma unroll
        for (int j = 0; j < 8; ++j) acc[i][j] += av[i] * bv[j];
    }
  }

  // epilogue: y = acc + D*u
  const float D = D_skip[0];
#pragma unroll
  for (int i = 0; i < 8; ++i) {
    int l = l0 + mf + i;
    int off = (b * 2048 + l) * 512 + h0 + nf;
    float4 u0 = *(const float4*)&u[off];
    float4 u1 = *(const float4*)&u[off + 4];
    float4 o0 = make_float4(acc[i][0] + D * u0.x, acc[i][1] + D * u0.y,
                            acc[i][2] + D * u0.z, acc[i][3] + D * u0.w);
    float4 o1 = make_float4(acc[i][4] + D * u1.x, acc[i][5] + D * u1.y,
                            acc[i][6] + D * u1.z, acc[i][7] + D * u1.w);
    *(float4*)&y[off] = o0;
    *(float4*)&y[off + 4] = o1;
  }
}

extern "C" void kernel_launch(void* const* d_in, const int* in_sizes, int n_in,
                              void* d_out, int out_size, void* d_ws,
                              size_t ws_size, hipStream_t stream) {
  (void)in_sizes; (void)n_in; (void)out_size; (void)ws_size;
  const float* u = (const float*)d_in[0];
  const float* B_ssm = (const float*)d_in[1];
  const float* C_ssm = (const float*)d_in[2];
  const float* D_skip = (const float*)d_in[3];
  const float* log_dt = (const float*)d_in[4];
  float* y = (float*)d_out;
  float* keff = (float*)d_ws;  // 2048 floats

  prep_kernel<<<1, 256, 0, stream>>>(B_ssm, C_ssm, log_dt, keff);
  conv_kernel<<<1024, 256, 0, stream>>>(u, keff, D_skip, y);
}

// Round 2
// 312.367 us; speedup vs baseline: 2.8751x; 2.8751x over previous
//
#include <hip/hip_runtime.h>
#include <math.h>

// ---------------------------------------------------------------------------
// S4 conv:  y[b,l,h] = sum_{t<=l} keff[l-t]*u[b,t,h] + D*u[b,l,h]
//           keff[d] = K[2047-d]  =>  A[l][t] = krev[2047-l+t], krev[x]=K[x]
// prep (1 block):  expm -> A_bar, B_bar; doubling scans -> K[0..2047];
//                  writes krev_hi/lo (bf16 split) + D_lo cutoff to ws.
// conv (1024 blk): 128x128 tile bf16 MFMA (16x16x32), 2-product (Khi,Klo)*u,
//                  Toeplitz A-frags from 256-slot ring of 16B krev groups.
// ---------------------------------------------------------------------------

typedef short short8 __attribute__((ext_vector_type(8)));
typedef float f32x4 __attribute__((ext_vector_type(4)));

#define SWMASK 28
__device__ __forceinline__ int swz(int r, int c) {
  return (r << 6) + (c ^ (r & SWMASK));
}
__device__ __forceinline__ float Aval(int i, int j) {
  if (i > j)  return -(float)(sqrt(2.0 * i + 1.0) * sqrt(2.0 * j + 1.0));
  if (i == j) return -(float)(i + 1);
  return 0.0f;
}
__device__ __forceinline__ unsigned rne_bf16(float x) {
  unsigned u = __float_as_uint(x);
  return (u + 0x7FFFu + ((u >> 16) & 1u)) >> 16;
}
__device__ __forceinline__ float invfact(int k) {
  switch (k) {
    case 0: return 1.0f;            case 1: return 1.0f;
    case 2: return 0.5f;            case 3: return (float)(1.0/6.0);
    case 4: return (float)(1.0/24.0);       case 5: return (float)(1.0/120.0);
    case 6: return (float)(1.0/720.0);      case 7: return (float)(1.0/5040.0);
    case 8: return (float)(1.0/40320.0);    case 9: return (float)(1.0/362880.0);
    case 10: return (float)(1.0/3628800.0); case 11: return (float)(1.0/39916800.0);
    case 12: return (float)(1.0/479001600.0);
    case 13: return (float)(1.0/6227020800.0);
    case 14: return (float)(1.0/87178291200.0);
    default: return (float)(1.0/1307674368000.0);
  }
}

// 64x64x64 matmul in swizzled LDS. out = L*R (+ c0*I + c1*G1 + c2*G2 + c3*G3)
__device__ __forceinline__ void mm64(float* out, const float* L, const float* R,
                                     const float* G1, const float* G2,
                                     const float* G3, float c0, float c1,
                                     float c2, float c3, int addG, int tid) {
  __syncthreads();
  const int r0 = (tid & 15) << 2;
  const int c0i = (tid >> 4) << 2;
  float acc[4][4];
#pragma unroll
  for (int i = 0; i < 4; ++i)
#pragma unroll
    for (int j = 0; j < 4; ++j) acc[i][j] = 0.f;

#pragma unroll 4
  for (int k4 = 0; k4 < 64; k4 += 4) {
    float4 a[4], b[4];
#pragma unroll
    for (int i = 0; i < 4; ++i)
      a[i] = *(const float4*)&L[((r0 + i) << 6) + (k4 ^ ((r0 + i) & SWMASK))];
#pragma unroll
    for (int d = 0; d < 4; ++d)
      b[d] = *(const float4*)&R[((k4 + d) << 6) + (c0i ^ ((k4 + d) & SWMASK))];
    float bv[4][4];
#pragma unroll
    for (int d = 0; d < 4; ++d) {
      bv[d][0] = b[d].x; bv[d][1] = b[d].y; bv[d][2] = b[d].z; bv[d][3] = b[d].w;
    }
#pragma unroll
    for (int i = 0; i < 4; ++i) {
      float av[4];
      av[0] = a[i].x; av[1] = a[i].y; av[2] = a[i].z; av[3] = a[i].w;
#pragma unroll
      for (int d = 0; d < 4; ++d)
#pragma unroll
        for (int j = 0; j < 4; ++j) acc[i][j] += av[d] * bv[d][j];
    }
  }
  if (addG) {
#pragma unroll
    for (int i = 0; i < 4; ++i)
#pragma unroll
      for (int j = 0; j < 4; ++j) {
        int r = r0 + i, c = c0i + j;
        float g = c1 * G1[swz(r, c)] + c2 * G2[swz(r, c)] + c3 * G3[swz(r, c)];
        if (r == c) g += c0;
        acc[i][j] += g;
      }
  }
#pragma unroll
  for (int i = 0; i < 4; ++i) {
    float4 v = make_float4(acc[i][0], acc[i][1], acc[i][2], acc[i][3]);
    *(float4*)&out[((r0 + i) << 6) + (c0i ^ ((r0 + i) & SWMASK))] = v;
  }
  __syncthreads();
}

__global__ __launch_bounds__(256) void prep_kernel(
    const float* __restrict__ B_ssm, const float* __restrict__ C_ssm,
    const float* __restrict__ log_dt, unsigned* __restrict__ wsd,
    int* __restrict__ wsi) {
  __shared__ float b0[4096], b1[4096], b2[4096], b3[4096];
  const int tid = threadIdx.x;
  const float dtf = expf(log_dt[0]);

  // ||A||_1 -> scaling exponent
  float* red = b2;
  if (tid < 64) {
    double colsum = (double)(tid + 1);
    double pj = sqrt(2.0 * tid + 1.0);
    for (int i = tid + 1; i < 64; ++i) colsum += pj * sqrt(2.0 * i + 1.0);
    red[tid] = (float)colsum;
  }
  __syncthreads();
  float maxc = 0.f;
  for (int j2 = 0; j2 < 64; ++j2) maxc = fmaxf(maxc, red[j2]);
  const float eta = dtf * maxc;
  int sExp;
  { int e; frexpf(eta, &e); sExp = e > 0 ? e : 0; }
  const float scale = ldexpf(dtf, -sExp);
  __syncthreads();

  // X = (dt/2^s)*A  (b0)
  for (int idx = tid; idx < 4096; idx += 256) {
    int r = idx >> 6, c = idx & 63;
    b0[swz(r, c)] = scale * Aval(r, c);
  }
  // X2 = X*X (b1)
  mm64(b1, b0, b0, b0, b0, b0, 0, 0, 0, 0, 0, tid);
  // Taylor-15, PS-2 Horner. G7 -> b2
  {
    float cI = invfact(14), cX = invfact(15);
    for (int idx = tid; idx < 4096; idx += 256) {
      int r = idx >> 6, c = idx & 63;
      float g = cX * b0[swz(r, c)];
      if (r == c) g += cI;
      b2[swz(r, c)] = g;
    }
  }
  float* Pc = b2; float* Pn = b3;
#pragma unroll
  for (int mq = 6; mq >= 0; --mq) {
    mm64(Pn, Pc, b1, b0, b0, b0, invfact(2 * mq), invfact(2 * mq + 1), 0, 0, 1, tid);
    float* t = Pc; Pc = Pn; Pn = t;
  }
  for (int q = 0; q < sExp; ++q) {
    mm64(Pn, Pc, Pc, b0, b0, b0, 0, 0, 0, 0, 0, tid);
    float* t = Pc; Pc = Pn; Pn = t;
  }
  float* AB = Pc;   // A_bar, in {b2,b3}
  float* SC = Pn;   // scratch, the other

  // B into b1[0..63] (X2 dead)
  if (tid < 64) b1[tid] = B_ssm[tid];
  __syncthreads();
  // solve A x = (A_bar - I) B  on wave 0 (double, wave-lockstep)
  if (tid < 64) {
    double rhs = 0.0;
    for (int k = 0; k < 64; ++k)
      rhs += (double)AB[swz(tid, k)] * (double)b1[k];
    rhs -= (double)b1[tid];
    double xv = 0.0, accd = rhs;
    for (int j2 = 0; j2 < 64; ++j2) {
      if (tid == j2) xv = accd / (double)Aval(j2, j2);
      double xj = __shfl(xv, j2, 64);
      if (tid > j2) accd -= (double)Aval(tid, j2) * xj;
    }
    b0[swz(tid, 0)] = (float)xv;   // V col 0 = B_bar  (X dead -> V = b0)
  }
  __syncthreads();

  // V doubling: V[:,t+2^k] = M_k V[:,t],  M_0 = A_bar, M_{k+1} = M_k^2
  float* V = b0;
  float* T = b1;
  float* Mcur = AB;
  float* Moth = SC;
  for (int k = 0; k < 6; ++k) {
    mm64(T, Mcur, V, b0, b0, b0, 0, 0, 0, 0, 0, tid);
    int cnt = 1 << k;
    for (int idx = tid; idx < 64 * cnt; idx += 256) {
      int c = idx >> 6, r = idx & 63;
      V[swz(r, cnt + c)] = T[swz(r, c)];
    }
    __syncthreads();
    mm64(Moth, Mcur, Mcur, b0, b0, b0, 0, 0, 0, 0, 0, tid);
    float* tp = Mcur; Mcur = Moth; Moth = tp;
  }
  // Mcur = R = A_bar^64; Moth free -> W
  float* W = Moth;
  if (tid < 64) W[swz(0, tid)] = C_ssm[tid];
  __syncthreads();
  // W doubling: W[t+2^k,:] = W[t,:] N_k, N_0 = R
  float* Ncur = Mcur;
  float* Tslot = b1;
  for (int k = 0; k < 5; ++k) {
    mm64(Tslot, W, Ncur, b0, b0, b0, 0, 0, 0, 0, 0, tid);
    int cnt = 1 << k;
    for (int idx = tid; idx < 64 * cnt; idx += 256) {
      int r = idx >> 6, c = idx & 63;
      W[swz(cnt + r, c)] = Tslot[swz(r, c)];
    }
    __syncthreads();
    if (k < 4) {
      mm64(Ncur == Tslot ? Ncur : Tslot, Ncur, Ncur, b0, b0, b0, 0, 0, 0, 0, 0, tid);
      float* tp = Ncur; Ncur = Tslot; Tslot = tp;
    }
  }
  // K2d = W * V  (rows t'=0..31, cols t=0..63): K[64t'+t]
  float* Kd = Tslot;  // in {b1, old N slot}; != V, != W
  mm64(Kd, W, V, b0, b0, b0, 0, 0, 0, 0, 0, tid);

  // emit krev_hi/lo bf16 (dwords: hi [0..1095], lo [1096..2191]) + D_lo
  {
    float ssum = 0.f;
    unsigned hih[4], loh[4];
#pragma unroll
    for (int q2 = 0; q2 < 4; ++q2) {
      unsigned h2[2], l2[2];
#pragma unroll
      for (int qq = 0; qq < 2; ++qq) {
        int x = (tid << 3) + (q2 << 1) + qq;
        float v = Kd[swz(x >> 6, x & 63)];
        ssum += v * v;
        unsigned h = rne_bf16(v);
        float hf = __uint_as_float(h << 16);
        unsigned l = rne_bf16(v - hf);
        h2[qq] = h; l2[qq] = l;
      }
      hih[q2] = h2[0] | (h2[1] << 16);
      loh[q2] = l2[0] | (l2[1] << 16);
    }
#pragma unroll
    for (int q2 = 0; q2 < 4; ++q2) {
      wsd[(tid << 2) + q2] = hih[q2];
      wsd[1096 + (tid << 2) + q2] = loh[q2];
    }
    if (tid < 72) { wsd[1024 + tid] = 0u; wsd[2120 + tid] = 0u; }
    b0[tid] = ssum;  // partials (V dead; Kd != b0)
  }
  __syncthreads();
  if (tid == 0) {
    float accq = 0.f; int xt = 0;
    for (int jc = 255; jc >= 0; --jc) {
      float na = accq + b0[jc];
      if (na > 4e-8f) { xt = (jc + 1) << 3; break; }
      accq = na;
    }
    wsi[0] = 2048 - xt;   // skip chunks whose whole d-range < D_lo
  }
}

// ---------------------------------------------------------------------------
// conv kernel
// ---------------------------------------------------------------------------
__device__ __forceinline__ void stage_group(int e, unsigned* ring,
                                            const unsigned* krev) {
  if (e > 2168) return;  // reads never exceed e=2167
  int d0 = e >> 1;
  unsigned D0 = krev[d0], D1 = krev[d0 + 1], D2 = krev[d0 + 2],
           D3 = krev[d0 + 3], D4 = krev[d0 + 4];
  uint4 v;
  if (e & 1) {
    v.x = (D0 >> 16) | (D1 << 16); v.y = (D1 >> 16) | (D2 << 16);
    v.z = (D2 >> 16) | (D3 << 16); v.w = (D3 >> 16) | (D4 << 16);
  } else {
    v = make_uint4(D0, D1, D2, D3);
  }
  ((uint4*)ring)[e & 255] = v;
}

__global__ __launch_bounds__(256, 3) void conv_kernel(
    const float* __restrict__ u, const unsigned* __restrict__ wsd,
    const float* __restrict__ D_skip, float* __restrict__ y,
    const int* __restrict__ wsi) {
  __shared__ __align__(16) unsigned krevh[1096], krevl[1096];
  __shared__ __align__(16) unsigned ringh[1024], ringl[1024];  // 256 slots x16B
  __shared__ __align__(16) unsigned uf[2048];                  // 512 slots x16B

  const int tid = threadIdx.x;
  const int bid = blockIdx.x;
  const int bn = bid & 3, b = (bid >> 2) & 15, bm = 15 - (bid >> 6);
  const int l0 = bm << 7, h0 = bn << 7;

  for (int i = tid; i < 1096; i += 256) {
    krevh[i] = wsd[i];
    krevl[i] = wsd[1096 + i];
  }
  const int D_lo = wsi[0];
  int kt_lim = ((l0 + 127 - D_lo) >> 5) + 1;
  if (kt_lim < 0) kt_lim = 0;
  const int ktiles = 4 * bm + 4;
  if (kt_lim > ktiles) kt_lim = ktiles;

  const int e0 = 1920 - l0;
  __syncthreads();

  // ring init: groups e in [e0, e0+216) for both products
  for (int tsk = tid; tsk < 432; tsk += 256) {
    int pr = tsk >= 216;
    int e = e0 + (pr ? tsk - 216 : tsk);
    stage_group(e, pr ? ringl : ringh, pr ? krevl : krevh);
  }

  const int lane = tid & 63, w = tid >> 6;
  const int wm = w & 1, wn = w >> 1;
  const int g = lane >> 4, m = lane & 15;

  f32x4 acc[4][4];
#pragma unroll
  for (int i = 0; i < 4; ++i)
#pragma unroll
    for (int j = 0; j < 4; ++j) acc[i][j] = (f32x4){0.f, 0.f, 0.f, 0.f};

  for (int kt = 0; kt < kt_lim; ++kt) {
    const int t0 = kt << 5;
    __syncthreads();
    // stage u -> B-frag layout: slot s: jn=s>>6, gg=(s>>4)&3, hm=s&15
#pragma unroll
    for (int si = 0; si < 2; ++si) {
      int s = tid + (si << 8);
      int jn = s >> 6, gg = (s >> 4) & 3, hm = s & 15;
      const float* src = u + (((b << 11) + t0 + (gg << 3)) << 9) + h0 + (jn << 4) + hm;
      unsigned pk[4];
#pragma unroll
      for (int q = 0; q < 4; ++q) {
        unsigned lo16 = rne_bf16(src[(q << 10)]);          // t = +2q
        unsigned hi16 = rne_bf16(src[(q << 10) + 512]);    // t = +2q+1
        pk[q] = lo16 | (hi16 << 16);
      }
      ((uint4*)uf)[s] = make_uint4(pk[0], pk[1], pk[2], pk[3]);
    }
    // ring top-up for chunk kt+2
    if (tid < 64) {
      int e = e0 + 216 + (kt << 5) + (tid & 31);
      stage_group(e, (tid >= 32) ? ringl : ringh, (tid >= 32) ? krevl : krevh);
    }
    __syncthreads();

    // fragments
    const int ebase = 2047 - l0 + (kt << 5) - (wm << 6) - m + (g << 3);
    short8 ah[4], al[4], bf[4];
#pragma unroll
    for (int i = 0; i < 4; ++i) {
      int slot = (ebase - (i << 4)) & 255;
      ah[i] = ((const short8*)ringh)[slot];
      al[i] = ((const short8*)ringl)[slot];
    }
#pragma unroll
    for (int j = 0; j < 4; ++j)
      bf[j] = ((const short8*)uf)[(((wn << 2) + j) << 6) | lane];
#pragma unroll
    for (int i = 0; i < 4; ++i)
#pragma unroll
      for (int j = 0; j < 4; ++j) {
        acc[i][j] = __builtin_amdgcn_mfma_f32_16x16x32_bf16(ah[i], bf[j],
                                                            acc[i][j], 0, 0, 0);
        acc[i][j] = __builtin_amdgcn_mfma_f32_16x16x32_bf16(al[i], bf[j],
                                                            acc[i][j], 0, 0, 0);
      }
  }

  // epilogue: y = acc + D*u   (C/D: col = lane&15, row = (lane>>4)*4 + reg)
  const float D = D_skip[0];
#pragma unroll
  for (int i = 0; i < 4; ++i)
#pragma unroll
    for (int j = 0; j < 4; ++j) {
      int l = l0 + (wm << 6) + (i << 4) + (g << 2);
      int h = h0 + ((((wn << 2) + j)) << 4) + m;
      int off = (((b << 11) + l) << 9) + h;
#pragma unroll
      for (int r = 0; r < 4; ++r) {
        float uv = u[off + (r << 9)];
        y[off + (r << 9)] = acc[i][j][r] + D * uv;
      }
    }
}

extern "C" void kernel_launch(void* const* d_in, const int* in_sizes, int n_in,
                              void* d_out, int out_size, void* d_ws,
                              size_t ws_size, hipStream_t stream) {
  (void)in_sizes; (void)n_in; (void)out_size; (void)ws_size;
  const float* u = (const float*)d_in[0];
  const float* B_ssm = (const float*)d_in[1];
  const float* C_ssm = (const float*)d_in[2];
  const float* D_skip = (const float*)d_in[3];
  const float* log_dt = (const float*)d_in[4];
  float* y = (float*)d_out;
  unsigned* wsd = (unsigned*)d_ws;
  int* wsi = (int*)d_ws + 2192;

  prep_kernel<<<1, 256, 0, stream>>>(B_ssm, C_ssm, log_dt, wsd, wsi);
  conv_kernel<<<1024, 256, 0, stream>>>(u, wsd, D_skip, y, wsi);
}

// Round 4
// 245.843 us; speedup vs baseline: 3.6530x; 1.2706x over previous
//
#include <hip/hip_runtime.h>
#include <math.h>

// ---------------------------------------------------------------------------
// S4 conv:  y[b,l,h] = sum_{t<=l} K[2047-(l-t)]*u[t,h] + D*u[l,h]
//   A[l][t] = krev[2047-l+t], krev[x] = K[x]; D folded into krev[2047].
// prep_quant (block 0): expm(dt*A) via order-9 Taylor + scaling/squaring;
//   B_bar fp64 solve; log-depth doubling scans -> K; emits pre-shifted
//   ring tables rg_hi/rg_lo (16B groups krev16[e..e+7]) + cutoff.
// prep_quant (blocks 1..2048): quantize u -> bf16 B-fragment layout (ubf).
// conv (512 blocks): 128x128 bf16 MFMA, 2-product (Khi,Klo); tiles paired
//   (bm, 15-bm) for perfect balance; b-frags direct-global, prefetched.
//
// R3->R4 fix: in the three vectorized matvec sites, the swizzled float4
// matrix read yields columns (k4*4..+3) in ascending order (XOR cancels),
// so the PLAIN vector operand must be indexed at k4*4, not at the swizzled
// offset. R3 paired permuted entries for lanes with (lane&28)!=0.
// ---------------------------------------------------------------------------

typedef short short8 __attribute__((ext_vector_type(8)));
typedef float f32x4 __attribute__((ext_vector_type(4)));

#define SWMASK 28
__device__ __forceinline__ int swz(int r, int c) {
  return (r << 6) + (c ^ (r & SWMASK));
}
__device__ __forceinline__ float Aval(int i, int j) {
  if (i > j)  return -(float)(sqrt(2.0 * i + 1.0) * sqrt(2.0 * j + 1.0));
  if (i == j) return -(float)(i + 1);
  return 0.0f;
}
__device__ __forceinline__ unsigned rne_bf16(float x) {
  unsigned u = __float_as_uint(x);
  return (u + 0x7FFFu + ((u >> 16) & 1u)) >> 16;
}
__device__ __forceinline__ float invfact(int k) {
  switch (k) {
    case 0: return 1.0f;            case 1: return 1.0f;
    case 2: return 0.5f;            case 3: return (float)(1.0/6.0);
    case 4: return (float)(1.0/24.0);       case 5: return (float)(1.0/120.0);
    case 6: return (float)(1.0/720.0);      case 7: return (float)(1.0/5040.0);
    case 8: return (float)(1.0/40320.0);    default: return (float)(1.0/362880.0);
  }
}

// 64x64x64 fp32 matmul in swizzled LDS. out = L*R (+ cI*I + cX*Xg if addG).
__device__ __forceinline__ void mm64(float* out, const float* L, const float* R,
                                     const float* Xg, float cI, float cX,
                                     int addG, int tid) {
  __syncthreads();
  const int r0 = (tid & 15) << 2;
  const int c0 = (tid >> 4) << 2;
  float acc[4][4];
#pragma unroll
  for (int i = 0; i < 4; ++i)
#pragma unroll
    for (int j = 0; j < 4; ++j) acc[i][j] = 0.f;

#pragma unroll 4
  for (int k4 = 0; k4 < 64; k4 += 4) {
    float4 a[4], b[4];
#pragma unroll
    for (int i = 0; i < 4; ++i)
      a[i] = *(const float4*)&L[((r0 + i) << 6) + (k4 ^ ((r0 + i) & SWMASK))];
#pragma unroll
    for (int d = 0; d < 4; ++d)
      b[d] = *(const float4*)&R[((k4 + d) << 6) + (c0 ^ ((k4 + d) & SWMASK))];
    float bv[4][4];
#pragma unroll
    for (int d = 0; d < 4; ++d) {
      bv[d][0] = b[d].x; bv[d][1] = b[d].y; bv[d][2] = b[d].z; bv[d][3] = b[d].w;
    }
#pragma unroll
    for (int i = 0; i < 4; ++i) {
      float av[4];
      av[0] = a[i].x; av[1] = a[i].y; av[2] = a[i].z; av[3] = a[i].w;
#pragma unroll
      for (int d = 0; d < 4; ++d)
#pragma unroll
        for (int j = 0; j < 4; ++j) acc[i][j] += av[d] * bv[d][j];
    }
  }
  if (addG) {
#pragma unroll
    for (int i = 0; i < 4; ++i)
#pragma unroll
      for (int j = 0; j < 4; ++j) {
        int r = r0 + i, c = c0 + j;
        float gv = cX * Xg[swz(r, c)];
        if (r == c) gv += cI;
        acc[i][j] += gv;
      }
  }
#pragma unroll
  for (int i = 0; i < 4; ++i) {
    float4 v = make_float4(acc[i][0], acc[i][1], acc[i][2], acc[i][3]);
    *(float4*)&out[((r0 + i) << 6) + (c0 ^ ((r0 + i) & SWMASK))] = v;
  }
  __syncthreads();
}

__global__ __launch_bounds__(256) void prep_quant(
    const float* __restrict__ u, const float* __restrict__ B_ssm,
    const float* __restrict__ C_ssm, const float* __restrict__ D_skip,
    const float* __restrict__ log_dt, uint4* __restrict__ rg_hi,
    uint4* __restrict__ rg_lo, int* __restrict__ wsi,
    uint4* __restrict__ ubf) {
  __shared__ __align__(16) float smem[16384];  // 64 KB
  const int tid = threadIdx.x;

  if (blockIdx.x != 0) {
    // ---------------- u-quant block: (b, tc, half) -> ubf ----------------
    int q = blockIdx.x - 1;                 // 0..2047
    int b = q >> 7, rem = q & 127;
    int tc = rem >> 1, hf = rem & 1;
    int t0 = (tc << 5) + (hf << 4);
    float* S = smem;                        // [16][520]
#pragma unroll
    for (int r = 0; r < 8; ++r) {
      int s = tid + (r << 8);               // 2048 float4-slots
      int row = s >> 7, c4 = (s & 127) << 2;
      float4 v = *(const float4*)(u + ((((b << 11) + t0 + row) << 9) + c4));
      *(float4*)&S[row * 520 + c4] = v;
    }
    __syncthreads();
#pragma unroll
    for (int r = 0; r < 4; ++r) {
      int gidx = tid + (r << 8);            // 0..1023
      int jnG = gidx >> 5;                  // 0..31
      int gl = (gidx >> 4) & 1;
      int hm = gidx & 15;
      int gg = (hf << 1) | gl;
      int h = (jnG << 4) + hm;
      int tb = gl << 3;
      unsigned pk[4];
#pragma unroll
      for (int q2 = 0; q2 < 4; ++q2) {
        unsigned lo = rne_bf16(S[(tb + 2 * q2) * 520 + h]);
        unsigned hi = rne_bf16(S[(tb + 2 * q2 + 1) * 520 + h]);
        pk[q2] = lo | (hi << 16);
      }
      ubf[(((b << 6) | tc) << 11) | (jnG << 6) | (gg << 4) | hm] =
          make_uint4(pk[0], pk[1], pk[2], pk[3]);
    }
    return;
  }

  // ---------------- prep block ----------------
  float* b0 = smem;
  float* b1 = smem + 4096;
  float* b2 = smem + 8192;
  float* b3 = smem + 12288;
  const int lane = tid & 63, wv = tid >> 6;
  const float dtf = expf(log_dt[0]);

  // ||A||_1 -> scaling exponent (eta/2^s <= 0.5 for order-9 Taylor)
  if (tid < 64) {
    double cs = tid + 1.0, pj = sqrt(2.0 * tid + 1.0);
    for (int i = tid + 1; i < 64; ++i) cs += pj * sqrt(2.0 * i + 1.0);
    b2[tid] = (float)cs;
  }
  __syncthreads();
  float maxc = 0.f;
  for (int j = 0; j < 64; ++j) maxc = fmaxf(maxc, b2[j]);
  int E;
  frexpf(dtf * maxc, &E);
  int sExp = (E + 1) > 0 ? (E + 1) : 0;
  const float scale = ldexpf(dtf, -sExp);
  __syncthreads();

  // X -> b0
  for (int idx = tid; idx < 4096; idx += 256) {
    int r = idx >> 6, c = idx & 63;
    b0[swz(r, c)] = scale * Aval(r, c);
  }
  // X2 -> b1
  mm64(b1, b0, b0, b0, 0.f, 0.f, 0, tid);
  // G = c8*I + c9*X -> b2; Horner m=3..0: P = P*X2 + (c2m*I + c2m+1*X)
  for (int idx = tid; idx < 4096; idx += 256) {
    int r = idx >> 6, c = idx & 63;
    float gv = invfact(9) * b0[swz(r, c)];
    if (r == c) gv += invfact(8);
    b2[swz(r, c)] = gv;
  }
  float* Pc = b2;
  float* Pn = b3;
#pragma unroll
  for (int mq = 3; mq >= 0; --mq) {
    mm64(Pn, Pc, b1, b0, invfact(2 * mq), invfact(2 * mq + 1), 1, tid);
    float* t = Pc; Pc = Pn; Pn = t;
  }
  for (int q = 0; q < sExp; ++q) {
    mm64(Pn, Pc, Pc, b0, 0.f, 0.f, 0, tid);
    float* t = Pc; Pc = Pn; Pn = t;
  }
  // Pc = A_bar = M_0.  X, X2 dead -> Vt/Wt regions.
  float* Vt = b0;          // [64][68] spills into b1[0..255]
  float* Wt = b1 + 256;    // [32][68]
  float* Bl = b1 + 2500;   // 64 floats
  if (tid < 64) Bl[tid] = B_ssm[tid];
  __syncthreads();

  // B_bar: solve A x = (A_bar - I) B  (fp64, wave 0)
  // NOTE: swizzled float4 read of row i gives columns k4*4..k4*4+3 in
  // ascending order (XOR cancels) -> plain operand indexed at k4*4.
  if (tid < 64) {
    int i = tid;
    double accd = 0.0;
#pragma unroll
    for (int k4 = 0; k4 < 16; ++k4) {
      int jM = (k4 << 2) ^ (i & 28);
      float4 mv = *(const float4*)&Pc[(i << 6) + jM];
      float4 bv = *(const float4*)&Bl[k4 << 2];
      accd += (double)mv.x * bv.x + (double)mv.y * bv.y +
              (double)mv.z * bv.z + (double)mv.w * bv.w;
    }
    accd -= (double)Bl[i];
    double xv = 0.0;
    for (int j = 0; j < 64; ++j) {
      if (i == j) xv = accd / (double)Aval(j, j);
      double xj = __shfl(xv, j, 64);
      if (i > j) accd -= (double)Aval(i, j) * xj;
    }
    Vt[i] = (float)xv;  // Vt[0][i] = B_bar
  }
  __syncthreads();

  // V doubling: v_{t+2^k} = M_k v_t  (Pc = M_k), then square
  for (int k = 0; k < 6; ++k) {
    int cnt = 1 << k;
    for (int t = wv; t < cnt; t += 4) {
      float accv = 0.f;
#pragma unroll
      for (int k4 = 0; k4 < 16; ++k4) {
        int jM = (k4 << 2) ^ (lane & 28);
        float4 mv = *(const float4*)&Pc[(lane << 6) + jM];
        float4 vvv = *(const float4*)&Vt[t * 68 + (k4 << 2)];
        accv += mv.x * vvv.x + mv.y * vvv.y + mv.z * vvv.z + mv.w * vvv.w;
      }
      Vt[(t + cnt) * 68 + lane] = accv;
    }
    mm64(Pn, Pc, Pc, b0, 0.f, 0.f, 0, tid);  // leading barrier covers Vt
    float* t2 = Pc; Pc = Pn; Pn = t2;
  }
  // Pc = R = A_bar^64. Transpose -> Pn, continue chain on R^T.
  for (int idx = tid; idx < 4096; idx += 256) {
    int r = idx >> 6, c = idx & 63;
    Pn[swz(c, r)] = Pc[swz(r, c)];
  }
  __syncthreads();
  { float* t2 = Pc; Pc = Pn; Pn = t2; }
  if (tid < 64) Wt[lane] = C_ssm[lane];  // w_0 = C
  __syncthreads();
  // W doubling: w_{t+2^k} = (R^T)^{2^k} w_t
  for (int k = 0; k < 5; ++k) {
    int cnt = 1 << k;
    for (int t = wv; t < cnt; t += 4) {
      float accv = 0.f;
#pragma unroll
      for (int k4 = 0; k4 < 16; ++k4) {
        int jM = (k4 << 2) ^ (lane & 28);
        float4 mv = *(const float4*)&Pc[(lane << 6) + jM];
        float4 wvv = *(const float4*)&Wt[t * 68 + (k4 << 2)];
        accv += mv.x * wvv.x + mv.y * wvv.y + mv.z * wvv.z + mv.w * wvv.w;
      }
      Wt[(t + cnt) * 68 + lane] = accv;
    }
    if (k < 4) {
      mm64(Pn, Pc, Pc, b0, 0.f, 0.f, 0, tid);
      float* t2 = Pc; Pc = Pn; Pn = t2;
    } else {
      __syncthreads();
    }
  }

  // K[64t'+t] = w_t' . v_t  -> K in Pn (dead matrix buffer)
  float* K = Pn;
  for (int x = tid; x < 2048; x += 256) {
    int tp = x >> 6, t = x & 63;
    float dot = 0.f;
#pragma unroll
    for (int i4 = 0; i4 < 64; i4 += 4) {
      float4 wvv = *(const float4*)&Wt[tp * 68 + i4];
      float4 vvv = *(const float4*)&Vt[t * 68 + i4];
      dot += wvv.x * vvv.x + wvv.y * vvv.y + wvv.z * vvv.z + wvv.w * vvv.w;
    }
    K[x] = dot;
  }
  __syncthreads();

  // split (with D folded at x=2047) -> kh/kl; suffix-energy partials
  unsigned short* kh = (unsigned short*)Pc;
  unsigned short* kl = kh + 2192;
  float* ss = (float*)(kh + 4400);
  const float D = D_skip[0];
  for (int x = tid; x < 2192; x += 256) {
    float v = 0.f;
    if (x < 2048) { v = K[x]; if (x == 2047) v += D; }
    unsigned h = rne_bf16(v);
    float hf2 = __uint_as_float(h << 16);
    unsigned l = rne_bf16(v - hf2);
    kh[x] = (unsigned short)h;
    kl[x] = (unsigned short)l;
  }
  {
    float ssum = 0.f;
#pragma unroll
    for (int q = 0; q < 8; ++q) {
      int x = (tid << 3) + q;
      float v = K[x];
      if (x == 2047) v += D;
      ssum += v * v;
    }
    ss[tid] = ssum;
  }
  __syncthreads();

  // ring tables: rg[e] = krev16[e..e+7]
  for (int e = tid; e < 2176; e += 256) {
    unsigned ph[4], pl[4];
#pragma unroll
    for (int q2 = 0; q2 < 4; ++q2) {
      ph[q2] = (unsigned)kh[e + 2 * q2] | ((unsigned)kh[e + 2 * q2 + 1] << 16);
      pl[q2] = (unsigned)kl[e + 2 * q2] | ((unsigned)kl[e + 2 * q2 + 1] << 16);
    }
    rg_hi[e] = make_uint4(ph[0], ph[1], ph[2], ph[3]);
    rg_lo[e] = make_uint4(pl[0], pl[1], pl[2], pl[3]);
  }
  if (tid == 0) {
    float accq = 0.f;
    int xt = 0;
    for (int jc = 255; jc >= 0; --jc) {
      float na = accq + ss[jc];
      if (na > 4e-8f) { xt = (jc + 1) << 3; break; }
      accq = na;
    }
    wsi[0] = 2048 - xt;
  }
}

// ---------------------------------------------------------------------------
// conv kernel
// ---------------------------------------------------------------------------
__device__ __forceinline__ void load_bfrag(short8* bf, const uint4* ubf,
                                           const float* u, int use_ubf, int b,
                                           int kt, int h0, int wn, int lane) {
  if (use_ubf) {
    const short8* base = (const short8*)(ubf + ((((b << 6) | kt) << 11) |
                                               (((h0 >> 4) + (wn << 2)) << 6) |
                                               lane));
#pragma unroll
    for (int j = 0; j < 4; ++j) bf[j] = base[j << 6];
  } else {
    int gg = lane >> 4, hm = lane & 15;
#pragma unroll
    for (int j = 0; j < 4; ++j) {
      const float* src = u + ((((b << 11) + (kt << 5) + (gg << 3)) << 9) + h0 +
                              (((wn << 2) + j) << 4) + hm);
      unsigned pk[4];
#pragma unroll
      for (int q = 0; q < 4; ++q) {
        unsigned lo = rne_bf16(src[q << 10]);
        unsigned hi = rne_bf16(src[(q << 10) + 512]);
        pk[q] = lo | (hi << 16);
      }
      uint4 vv = make_uint4(pk[0], pk[1], pk[2], pk[3]);
      bf[j] = __builtin_bit_cast(short8, vv);
    }
  }
}

__global__ __launch_bounds__(256) void conv_kernel(
    const float* __restrict__ u, const uint4* __restrict__ rg_hi,
    const uint4* __restrict__ rg_lo, const uint4* __restrict__ ubf,
    const int* __restrict__ wsi, float* __restrict__ y, int use_ubf) {
  __shared__ __align__(16) unsigned ringh[1024], ringl[1024];  // 256x16B each
  const int tid = threadIdx.x;
  const int bid = blockIdx.x;
  const int b = bid >> 5;
  const int bn = bid & 3;
  const int pr = (bid >> 2) & 7;
  const int h0 = bn << 7;
  const int lane = tid & 63, w = tid >> 6;
  const int wm = w & 1, wn = w >> 1;
  const int g = lane >> 4, m = lane & 15;
  const int D_lo = wsi[0];

  for (int tile = 0; tile < 2; ++tile) {
    const int bm = tile ? pr : 15 - pr;
    const int l0 = bm << 7;
    const int e0 = 1920 - l0;
    const int ktiles = 4 * bm + 4;
    int kt_lim = ((l0 + 127 - D_lo) >> 5) + 1;
    if (kt_lim < 0) kt_lim = 0;
    if (kt_lim > ktiles) kt_lim = ktiles;

    __syncthreads();  // previous tile's ring reads complete
    for (int tsk = tid; tsk < 432; tsk += 256) {
      int isLo = tsk >= 216;
      int e = e0 + (isLo ? tsk - 216 : tsk);
      if (e <= 2175) {
        uint4 v = isLo ? rg_lo[e] : rg_hi[e];
        ((uint4*)(isLo ? ringl : ringh))[e & 255] = v;
      }
    }

    f32x4 acc[4][4];
#pragma unroll
    for (int i = 0; i < 4; ++i)
#pragma unroll
      for (int j = 0; j < 4; ++j) acc[i][j] = (f32x4){0.f, 0.f, 0.f, 0.f};

    short8 bcur[4];
    if (kt_lim > 0) load_bfrag(bcur, ubf, u, use_ubf, b, 0, h0, wn, lane);

    for (int kt = 0; kt < kt_lim; ++kt) {
      __syncthreads();  // ring writes visible
      // top-up read (for chunk kt+3's window) -- into registers
      uint4 tv;
      bool tdo = false;
      int tslot = 0;
      const bool tlo = (tid >= 32);
      if (tid < 64) {
        int te = e0 + 216 + (kt << 5) + (tid & 31);
        if (te <= 2175) {
          tv = tlo ? rg_lo[te] : rg_hi[te];
          tdo = true;
          tslot = te & 255;
        }
      }
      // A-fragments from ring
      const int ebase = 2047 - l0 + (kt << 5) - (wm << 6) - m + (g << 3);
      short8 ah[4], al[4];
#pragma unroll
      for (int i = 0; i < 4; ++i) {
        int slot = (ebase - (i << 4)) & 255;
        ah[i] = ((const short8*)ringh)[slot];
        al[i] = ((const short8*)ringl)[slot];
      }
      // prefetch next b-frags
      short8 bnx[4];
      if (kt + 1 < kt_lim)
        load_bfrag(bnx, ubf, u, use_ubf, b, kt + 1, h0, wn, lane);
#pragma unroll
      for (int i = 0; i < 4; ++i)
#pragma unroll
        for (int j = 0; j < 4; ++j) {
          acc[i][j] = __builtin_amdgcn_mfma_f32_16x16x32_bf16(ah[i], bcur[j],
                                                              acc[i][j], 0, 0, 0);
          acc[i][j] = __builtin_amdgcn_mfma_f32_16x16x32_bf16(al[i], bcur[j],
                                                              acc[i][j], 0, 0, 0);
        }
      if (tdo) ((uint4*)(tlo ? ringl : ringh))[tslot] = tv;
      if (kt + 1 < kt_lim) {
#pragma unroll
        for (int j = 0; j < 4; ++j) bcur[j] = bnx[j];
      }
    }

    // epilogue: y = acc  (D folded into K); C/D: col=lane&15, row=g*4+reg
#pragma unroll
    for (int i = 0; i < 4; ++i)
#pragma unroll
      for (int j = 0; j < 4; ++j) {
        int l = l0 + (wm << 6) + (i << 4) + (g << 2);
        int h = h0 + (((wn << 2) + j) << 4) + m;
        int off = (((b << 11) + l) << 9) + h;
#pragma unroll
        for (int r = 0; r < 4; ++r) y[off + (r << 9)] = acc[i][j][r];
      }
  }
}

extern "C" void kernel_launch(void* const* d_in, const int* in_sizes, int n_in,
                              void* d_out, int out_size, void* d_ws,
                              size_t ws_size, hipStream_t stream) {
  (void)in_sizes; (void)n_in; (void)out_size;
  const float* u = (const float*)d_in[0];
  const float* B_ssm = (const float*)d_in[1];
  const float* C_ssm = (const float*)d_in[2];
  const float* D_skip = (const float*)d_in[3];
  const float* log_dt = (const float*)d_in[4];
  float* y = (float*)d_out;

  const size_t UBF_BYTES = (size_t)16 * 64 * 2048 * 16;  // 32 MB
  const size_t RG_BYTES = (size_t)2176 * 16 * 2 + 256;
  int use_ubf = (ws_size >= UBF_BYTES + RG_BYTES) ? 1 : 0;
  char* wsb = (char*)d_ws;
  uint4* ubf = (uint4*)wsb;
  uint4* rg_hi = use_ubf ? (uint4*)(wsb + UBF_BYTES) : (uint4*)wsb;
  uint4* rg_lo = rg_hi + 2176;
  int* wsi = (int*)(rg_lo + 2176);

  prep_quant<<<use_ubf ? 2049 : 1, 256, 0, stream>>>(
      u, B_ssm, C_ssm, D_skip, log_dt, rg_hi, rg_lo, wsi, ubf);
  conv_kernel<<<512, 256, 0, stream>>>(u, rg_hi, rg_lo, ubf, wsi, y, use_ubf);
}